// Round 10
// baseline (149.841 us; speedup 1.0000x reference)
//
#include <hip/hip_runtime.h>

// SheafConnectionLayer: out = x; for each edge e (both directions):
//   fwd: m = T[e]   @ x[a] - x[b], scatter to b, weight softplus(raw_w[e])
//   rev: m = T[E+e] @ x[b] - x[a], scatter to a, weight softplus(raw_w[E+e])
//   out[s] += (alpha * w / max(deg[s],1)) * m
//
// BW-bound on the one-shot 819 MB T stream. Each 16-lane group reads each
// 1KB T tile as 4 instructions x 256B fully-contiguous fully-used data
// (lane d, instr j -> 16B at tile + j*256 + d*16); every T byte touched
// exactly once -> nontemporal loads keep L2/L3 for x/out/ei/deg.
//
// 2-edge batching: each group handles edges {2p, 2p+1}, both directions:
// 16 nt T loads (4KB) issued up-front per iteration; ei reads are two
// aligned int2 loads. x[a]/x[b] float4 gathers double as the matvec
// operand of one direction and the x_s subtrahend of the other (r_out =
// cc+q lies in the lane's own col chunk, so xs = chunk[q]).
//
// NOTE (round 9 finding): gfx950 has NO packed-f32 global atomic
// (global_atomic_pk_add_f32 rejected by the assembler; only _f16/_bf16
// pk variants exist). Scalar global_atomic_add_f32 per row is the only
// correct scatter primitive here — atomic op count is not reducible.
//
// out=x init is a dedicated kernel (NOT hipMemcpyAsync): a captured D2D
// memcpy node rides the SDMA path and its edge to the kernel node proved
// unreliable under graph replay (round 5: post-timing absmax 3.17 == |x|).

static constexpr int DD = 16;

typedef float f4 __attribute__((ext_vector_type(4)));

__global__ __launch_bounds__(256) void init_out(
    const f4* __restrict__ x4, f4* __restrict__ out4, int n4)
{
    const int i = blockIdx.x * blockDim.x + threadIdx.x;
    if (i < n4) out4[i] = x4[i];
}

__device__ __forceinline__ float dot_rows(
    const f4 m0, const f4 m1, const f4 m2, const f4 m3,
    const f4 xg, const int sel)
{
    float p0 = m0.x*xg.x + m0.y*xg.y + m0.z*xg.z + m0.w*xg.w;
    float p1 = m1.x*xg.x + m1.y*xg.y + m1.z*xg.z + m1.w*xg.w;
    float p2 = m2.x*xg.x + m2.y*xg.y + m2.z*xg.z + m2.w*xg.w;
    float p3 = m3.x*xg.x + m3.y*xg.y + m3.z*xg.z + m3.w*xg.w;
    p0 += __shfl_xor(p0, 1);  p0 += __shfl_xor(p0, 2);
    p1 += __shfl_xor(p1, 1);  p1 += __shfl_xor(p1, 2);
    p2 += __shfl_xor(p2, 1);  p2 += __shfl_xor(p2, 2);
    p3 += __shfl_xor(p3, 1);  p3 += __shfl_xor(p3, 2);
    return (sel == 0) ? p0 : (sel == 1) ? p1 : (sel == 2) ? p2 : p3;
}

__device__ __forceinline__ float softplus_f(const float v)
{
    return fmaxf(v, 0.0f) + log1pf(__expf(-fabsf(v)));
}

__device__ __forceinline__ float comp_q(const f4 v, const int q)
{
    return (q == 0) ? v.x : (q == 1) ? v.y : (q == 2) ? v.z : v.w;
}

__global__ __launch_bounds__(256) void sheaf_edges(
    const float* __restrict__ x,
    const int*   __restrict__ ei,     // [2*E] : src rows then dst rows
    const float* __restrict__ deg,    // [N]
    const float* __restrict__ T,      // [2E][16][16]
    const float* __restrict__ raw_w,  // [2E]
    const float* __restrict__ alpha_p,// [1]
    float*       __restrict__ out,    // [N][16], pre-initialized to x
    int E)
{
    const float alpha = alpha_p[0];
    const int lane16 = threadIdx.x & 15;
    const int q   = lane16 >> 2;         // row offset within each quad (0..3)
    const int cc  = (lane16 & 3) << 2;   // col chunk base (0,4,8,12)
    const int sel = lane16 & 3;
    const int r_out = cc + q;            // output row this lane owns
    const int group0  = (blockIdx.x * blockDim.x + threadIdx.x) >> 4;
    const int gstride = (gridDim.x * blockDim.x) >> 4;
    const int npairs  = E >> 1;

    for (int p = group0; p < npairs; p += gstride) {
        const int eA = 2 * p;            // edge pair {eA, eA+1}

        // 16 nt T loads (4 tiles x 4 chunks = 4KB) batched up-front.
        const f4* TfA = reinterpret_cast<const f4*>(T + (size_t)eA * 256) + lane16;
        const f4* TrA = reinterpret_cast<const f4*>(T + ((size_t)E + eA) * 256) + lane16;
        const f4 fA0 = __builtin_nontemporal_load(TfA +  0);
        const f4 fA1 = __builtin_nontemporal_load(TfA + 16);
        const f4 fA2 = __builtin_nontemporal_load(TfA + 32);
        const f4 fA3 = __builtin_nontemporal_load(TfA + 48);
        const f4 fB0 = __builtin_nontemporal_load(TfA + 64);   // tile eA+1
        const f4 fB1 = __builtin_nontemporal_load(TfA + 80);
        const f4 fB2 = __builtin_nontemporal_load(TfA + 96);
        const f4 fB3 = __builtin_nontemporal_load(TfA + 112);
        const f4 rA0 = __builtin_nontemporal_load(TrA +  0);
        const f4 rA1 = __builtin_nontemporal_load(TrA + 16);
        const f4 rA2 = __builtin_nontemporal_load(TrA + 32);
        const f4 rA3 = __builtin_nontemporal_load(TrA + 48);
        const f4 rB0 = __builtin_nontemporal_load(TrA + 64);   // tile E+eA+1
        const f4 rB1 = __builtin_nontemporal_load(TrA + 80);
        const f4 rB2 = __builtin_nontemporal_load(TrA + 96);
        const f4 rB3 = __builtin_nontemporal_load(TrA + 112);

        // edge endpoints: int2 (eA even -> 8B aligned; E even)
        const int2 aa = *reinterpret_cast<const int2*>(ei + eA);      // src
        const int2 bb = *reinterpret_cast<const int2*>(ei + E + eA);  // dst
        const f4 xa0 = *reinterpret_cast<const f4*>(x + (size_t)aa.x * DD + cc);
        const f4 xb0 = *reinterpret_cast<const f4*>(x + (size_t)bb.x * DD + cc);
        const f4 xa1 = *reinterpret_cast<const f4*>(x + (size_t)aa.y * DD + cc);
        const f4 xb1 = *reinterpret_cast<const f4*>(x + (size_t)bb.y * DD + cc);

        const float dotF0 = dot_rows(fA0, fA1, fA2, fA3, xa0, sel);
        const float dotR0 = dot_rows(rA0, rA1, rA2, rA3, xb0, sel);
        const float dotF1 = dot_rows(fB0, fB1, fB2, fB3, xa1, sel);
        const float dotR1 = dot_rows(rB0, rB1, rB2, rB3, xb1, sel);

        const float wF0 = softplus_f(raw_w[eA]);
        const float wF1 = softplus_f(raw_w[eA + 1]);
        const float wR0 = softplus_f(raw_w[E + eA]);
        const float wR1 = softplus_f(raw_w[E + eA + 1]);

        const float cF0 = alpha * wF0 / fmaxf(deg[bb.x], 1.0f);
        const float cR0 = alpha * wR0 / fmaxf(deg[aa.x], 1.0f);
        const float cF1 = alpha * wF1 / fmaxf(deg[bb.y], 1.0f);
        const float cR1 = alpha * wR1 / fmaxf(deg[aa.y], 1.0f);

        atomicAdd(out + (size_t)bb.x * DD + r_out, cF0 * (dotF0 - comp_q(xb0, q)));
        atomicAdd(out + (size_t)aa.x * DD + r_out, cR0 * (dotR0 - comp_q(xa0, q)));
        atomicAdd(out + (size_t)bb.y * DD + r_out, cF1 * (dotF1 - comp_q(xb1, q)));
        atomicAdd(out + (size_t)aa.y * DD + r_out, cR1 * (dotR1 - comp_q(xa1, q)));
    }

    // odd-E tail (not hit for E=400000, kept for correctness)
    if ((E & 1) && group0 == 0) {
        const int e = E - 1;
        const f4* Tf = reinterpret_cast<const f4*>(T + (size_t)e * 256) + lane16;
        const f4* Tr = reinterpret_cast<const f4*>(T + ((size_t)E + e) * 256) + lane16;
        const f4 f0 = Tf[0], f1 = Tf[16], f2 = Tf[32], f3 = Tf[48];
        const f4 r0 = Tr[0], r1 = Tr[16], r2 = Tr[32], r3 = Tr[48];
        const int a = ei[e], b = ei[E + e];
        const f4 xa = *reinterpret_cast<const f4*>(x + (size_t)a * DD + cc);
        const f4 xb = *reinterpret_cast<const f4*>(x + (size_t)b * DD + cc);
        const float dotF = dot_rows(f0, f1, f2, f3, xa, sel);
        const float dotR = dot_rows(r0, r1, r2, r3, xb, sel);
        const float cF = alpha * softplus_f(raw_w[e])     / fmaxf(deg[b], 1.0f);
        const float cR = alpha * softplus_f(raw_w[E + e]) / fmaxf(deg[a], 1.0f);
        atomicAdd(out + (size_t)b * DD + r_out, cF * (dotF - comp_q(xb, q)));
        atomicAdd(out + (size_t)a * DD + r_out, cR * (dotR - comp_q(xa, q)));
    }
}

extern "C" void kernel_launch(void* const* d_in, const int* in_sizes, int n_in,
                              void* d_out, int out_size, void* d_ws, size_t ws_size,
                              hipStream_t stream) {
    const float* x       = (const float*)d_in[0];
    const int*   ei      = (const int*)  d_in[1];
    const float* deg     = (const float*)d_in[2];
    const float* T       = (const float*)d_in[3];
    const float* raw_w   = (const float*)d_in[4];
    const float* alpha_p = (const float*)d_in[5];
    float* out = (float*)d_out;

    const int E = in_sizes[1] / 2;    // edge_index is (2, E)

    // out = x via kernel (same-stream kernel->kernel ordering is reliable
    // under graph capture; captured SDMA memcpy nodes were not).
    const int n4 = out_size / 4;      // out_size = N*16, divisible by 4
    init_out<<<(n4 + 255) / 256, 256, 0, stream>>>(
        reinterpret_cast<const f4*>(x), reinterpret_cast<f4*>(out), n4);

    const int threads = 256;
    const int blocks  = 2048;         // grid-stride over E/2 edge pairs
    sheaf_edges<<<blocks, threads, 0, stream>>>(x, ei, deg, T, raw_w, alpha_p,
                                                out, E);
}